// Round 2
// baseline (133.817 us; speedup 1.0000x reference)
//
#include <hip/hip_runtime.h>

#define B_ 8
#define N_ 512
#define F_ 128
#define H_ 4
#define U_ 32
#define LEAKY_ALPHA 0.2f

// ---------------------------------------------------------------------------
// Kernel 1: projections.
//   hsrc[b,h,n,u]  =  sum_f x[b,n,f] * Wsrc[h,f,u]
//   hdstN[b,h,n,u] = -sum_f x[b,n,f] * Wdst[h,f,u]      (negated!)
//   Drow[b,h,n]    =  sum_u a[h,u] * h_dst[b,h,n,u]     (true, un-negated D)
// Score identity used downstream (row-constant 0.2*A_i dropped — softmax
// is shift-invariant per row):
//   score(i,j) ~ D_j + 0.8 * sum_u a_u * max(s_iu, -d_ju)
// Block = 8 flat rows, 512 blocks (2/CU). Thread = one of 256 output cols.
// ---------------------------------------------------------------------------
__global__ __launch_bounds__(256) void proj_kernel(
    const float* __restrict__ x, const float* __restrict__ Wsrc,
    const float* __restrict__ Wdst, const float* __restrict__ a,
    float* __restrict__ hsrc, float* __restrict__ hdstN,
    float* __restrict__ Drow)
{
    __shared__ float4 xlds[8 * 32];           // 8 rows x 128 floats
    const int t  = threadIdx.x;
    const int r0 = blockIdx.x * 8;            // first flat row (b*N+n)

    const float4* xg = (const float4*)x + (size_t)r0 * 32;
    xlds[t] = xg[t];
    __syncthreads();

    const int u     = t & 31;
    const int h     = (t >> 5) & 3;
    const int which = t >> 7;                 // 0 = src, 1 = dst
    const float* W  = (which ? Wdst : Wsrc) + h * (F_ * U_) + u;

    float acc[8];
#pragma unroll
    for (int r = 0; r < 8; ++r) acc[r] = 0.f;

#pragma unroll 2
    for (int fc = 0; fc < 32; ++fc) {
        const float w0 = W[(4 * fc + 0) * U_];
        const float w1 = W[(4 * fc + 1) * U_];
        const float w2 = W[(4 * fc + 2) * U_];
        const float w3 = W[(4 * fc + 3) * U_];
#pragma unroll
        for (int r = 0; r < 8; ++r) {
            const float4 xv = xlds[r * 32 + fc];
            float s = acc[r];
            s = fmaf(xv.x, w0, s);
            s = fmaf(xv.y, w1, s);
            s = fmaf(xv.z, w2, s);
            s = fmaf(xv.w, w3, s);
            acc[r] = s;
        }
    }

    const float av = a[h * U_ + u];

#pragma unroll
    for (int r = 0; r < 8; ++r) {
        const int row = r0 + r;               // = b*N + n
        const int b = row >> 9, n = row & (N_ - 1);
        const size_t base = ((size_t)((b * H_ + h) * N_ + n) << 5) + u;
        if (which == 0) {
            hsrc[base] = acc[r];
        } else {
            hdstN[base] = -acc[r];            // store negated d
            // reduce a_u * d over the 32 u-lanes
            float v = acc[r] * av;
            v += __shfl_xor(v, 1);
            v += __shfl_xor(v, 2);
            v += __shfl_xor(v, 4);
            v += __shfl_xor(v, 8);
            v += __shfl_xor(v, 16);
            if (u == 0) Drow[(b * H_ + h) * N_ + n] = v;
        }
    }
}

// ---------------------------------------------------------------------------
// Kernel 2: attention. Block = (b, h, tile of 16 i-rows), 256 threads.
// Thread = (i = t>>4, sub = t&15). Only ONE 18.4 KB LDS buffer (the 128-row
// staging tile, rows padded to 36 floats). Scores/p never leave registers;
// phase C accumulates 32 u-partials per thread over its own 32 j's, then a
// 4-round butterfly (xor 1,2,4,8 — within the 16 sub-lanes of each i) sums
// across sub-lanes with static register slots (cndmask halves, no dynamic
// register indexing).
// ---------------------------------------------------------------------------
#define DT_STRIDE 36

__global__ __launch_bounds__(256) void attn_kernel(
    const float* __restrict__ hsrc, const float* __restrict__ hdstN,
    const float* __restrict__ Drow, const float* __restrict__ a,
    float* __restrict__ out)
{
    __shared__ float dt[128 * DT_STRIDE];     // 18.4 KB staging tile

    const int t    = threadIdx.x;
    const int tile = blockIdx.x & 31;
    const int bh   = blockIdx.x >> 5;         // b*H + h
    const int h    = bh & 3;
    const int b    = bh >> 2;
    const int i    = t >> 4;
    const int sub  = t & 15;
    const int iglob = tile * 16 + i;
    const size_t bhN = (size_t)bh * N_;

    float sc[32];

    // ---------------- Phase A: scores -> registers ----------------
    {
        float4 s4[8], a4[8];
        const float4* sg = (const float4*)(hsrc + ((bhN + iglob) << 5));
        const float4* ag = (const float4*)(a + h * U_);
#pragma unroll
        for (int q = 0; q < 8; ++q) s4[q] = sg[q];
#pragma unroll
        for (int q = 0; q < 8; ++q) a4[q] = ag[q];

        for (int jt = 0; jt < 4; ++jt) {
            __syncthreads();
            const float4* dg = (const float4*)(hdstN + ((bhN + jt * 128) << 5));
#pragma unroll
            for (int q = 0; q < 4; ++q) {
                const int idx = t + 256 * q;
                const int j = idx >> 3, uq = idx & 7;
                *(float4*)&dt[j * DT_STRIDE + uq * 4] = dg[idx];
            }
            __syncthreads();
#pragma unroll
            for (int k = 0; k < 8; ++k) {
                const int jl = sub + 16 * k;
                const float4* dr = (const float4*)&dt[jl * DT_STRIDE];
                float rsum = 0.f;
#pragma unroll
                for (int q = 0; q < 8; ++q) {
                    const float4 dv = dr[q];      // = -d
                    const float4 sv = s4[q];
                    const float4 av = a4[q];
                    rsum = fmaf(fmaxf(sv.x, dv.x), av.x, rsum);
                    rsum = fmaf(fmaxf(sv.y, dv.y), av.y, rsum);
                    rsum = fmaf(fmaxf(sv.z, dv.z), av.z, rsum);
                    rsum = fmaf(fmaxf(sv.w, dv.w), av.w, rsum);
                }
                const float Dj = Drow[bhN + jt * 128 + jl];
                sc[jt * 8 + k] = Dj + (1.f - LEAKY_ALPHA) * rsum;
            }
        }
    }

    // ---------------- Phase B: softmax (p stays in sc) ----------------
    float m = sc[0];
#pragma unroll
    for (int r = 1; r < 32; ++r) m = fmaxf(m, sc[r]);
    m = fmaxf(m, __shfl_xor(m, 1));
    m = fmaxf(m, __shfl_xor(m, 2));
    m = fmaxf(m, __shfl_xor(m, 4));
    m = fmaxf(m, __shfl_xor(m, 8));

    float sum = 0.f;
#pragma unroll
    for (int r = 0; r < 32; ++r) {
        const float e = __expf(sc[r] - m);
        sum += e;
        sc[r] = e;                            // sc now holds p (unnormalized)
    }
    sum += __shfl_xor(sum, 1);
    sum += __shfl_xor(sum, 2);
    sum += __shfl_xor(sum, 4);
    sum += __shfl_xor(sum, 8);
    const float inv = __builtin_amdgcn_rcpf(sum);

    // ---------------- Phase C: out = (p @ h_src) * inv ----------------
    float o[32];
#pragma unroll
    for (int r = 0; r < 32; ++r) o[r] = 0.f;

    for (int jt = 0; jt < 4; ++jt) {
        __syncthreads();
        const float4* sg = (const float4*)(hsrc + ((bhN + jt * 128) << 5));
#pragma unroll
        for (int q = 0; q < 4; ++q) {
            const int idx = t + 256 * q;
            const int j = idx >> 3, uq = idx & 7;
            *(float4*)&dt[j * DT_STRIDE + uq * 4] = sg[idx];
        }
        __syncthreads();
#pragma unroll
        for (int k = 0; k < 8; ++k) {
            const int jl = sub + 16 * k;
            const float pj = sc[jt * 8 + k];
            const float4* sr = (const float4*)&dt[jl * DT_STRIDE];
#pragma unroll
            for (int q = 0; q < 8; ++q) {
                const float4 v = sr[q];
                o[4 * q + 0] = fmaf(pj, v.x, o[4 * q + 0]);
                o[4 * q + 1] = fmaf(pj, v.y, o[4 * q + 1]);
                o[4 * q + 2] = fmaf(pj, v.z, o[4 * q + 2]);
                o[4 * q + 3] = fmaf(pj, v.w, o[4 * q + 3]);
            }
        }
    }

    // Butterfly-reduce o[32] across the 16 sub-lanes of this i.
    // Round k: partner = sub ^ (1<<k); hi lane keeps upper half of live slots.
#pragma unroll
    for (int k = 0; k < 4; ++k) {
        const int mask = 1 << k;
        const int half = 16 >> k;             // live slots after round: half
        const bool hi = (sub >> k) & 1;
#pragma unroll
        for (int s = 0; s < 16; ++s) {
            if (s < half) {
                const float send = hi ? o[s] : o[s + half];
                const float recv = __shfl_xor(send, mask);
                const float keep = hi ? o[s + half] : o[s];
                o[s] = keep + recv;
            }
        }
    }
    // lane (i,sub) now holds u = {2*rev4(sub), 2*rev4(sub)+1} in o[0],o[1]
    const int rev = ((sub & 1) << 3) | ((sub & 2) << 1) |
                    ((sub & 4) >> 1) | ((sub & 8) >> 3);
    const int u0 = rev * 2;

    float2 ov;
    ov.x = o[0] * inv;
    ov.y = o[1] * inv;
    *(float2*)&out[(size_t)(b * N_ + iglob) * (H_ * U_) + h * U_ + u0] = ov;
}

// ---------------------------------------------------------------------------
extern "C" void kernel_launch(void* const* d_in, const int* in_sizes, int n_in,
                              void* d_out, int out_size, void* d_ws, size_t ws_size,
                              hipStream_t stream) {
    const float* x    = (const float*)d_in[0];
    const float* Wsrc = (const float*)d_in[1];
    const float* Wdst = (const float*)d_in[2];
    const float* a    = (const float*)d_in[3];

    float* ws    = (float*)d_ws;
    float* hsrc  = ws;
    float* hdstN = hsrc + (size_t)B_ * H_ * N_ * U_;
    float* Drow  = hdstN + (size_t)B_ * H_ * N_ * U_;

    proj_kernel<<<(B_ * N_) / 8, 256, 0, stream>>>(x, Wsrc, Wdst, a,
                                                   hsrc, hdstN, Drow);
    attn_kernel<<<B_ * H_ * (N_ / 16), 256, 0, stream>>>(hsrc, hdstN, Drow,
                                                         a, (float*)d_out);
}